// Round 4
// baseline (346.846 us; speedup 1.0000x reference)
//
#include <hip/hip_runtime.h>
#include <hip/hip_bf16.h>

// GateAttentionUnit. B=16, N=512, D=1024, E=2048, S=128, F=2E+S=4224.
// CONFIRMED: all 10 inputs fp32, output fp32. Internal compute bf16 MFMA.
//
// Pipeline:
//   K0 rope_table: cos/sin[512][64] fp32 -> d_out scratch
//   K0b cvt uv_w -> bf16 (d_out scratch); K0c cvt o_w -> bf16 (ws)
//   K1 ln:         x -> xn bf16 (d_out scratch)                    [8192 x 1024]
//   K2 gemm<EpiUV>: silu(xn @ uv_wb^T + uv_b) -> u | vT | base     [8192 x 4224]
//   K3 rope_qk:    q,k = rope(base*gamma+beta) (d_out scratch)     [8192 x 128]
//   K4 gemm<EpiQK>:   km = relu(q@k^T/512 + relpos)^2 (d_out)      [16][512][512]
//   K5 gemm<EpiAttn>: out2 = u * (km @ vT^T), out2 aliases u       [8192 x 2048]
//   K6 gemm<EpiOut>:  out = out2 @ o_wb^T + o_b + x  (fp32 out)    [8192 x 1024]
//
// R10 -> R11: gemm_nt gets (a) double-buffered LDS (2x32KB), stage(t+1)
// issued BEFORE waiting on tile t; (b) __syncthreads -> raw s_barrier pair
// with counted s_waitcnt vmcnt(8) (tile t's 8 loads retired; tile t+1's 8
// stay in flight across the barrier) -- removes the per-iter vmcnt(0) drain
// that was the ~45% stall (R10 counters: MfmaUtil 27.5 = VALUBusy 27.5,
// HBM 18%); (c) staging addresses hoisted out of the K-loop (was ~150
// cyc/iter VALU, equal to the MFMA time itself).
// Race-freedom: tile-(t+1) DMA writes target the buffer last READ in iter
// t-1, sealed by the trailing s_barrier (ds_reads complete before the last
// MFMA consumes them -> before the barrier). Tile-t reads guarded by each
// wave's vmcnt(8) BEFORE the leading barrier; barrier release => all waves'
// tile-t loads landed. No __syncthreads anywhere in the hot loop.
//
// ws (68 MiB; >=69.4 MiB proven available in R5):
//   u [0,32M) (K2->K5; out2 alias K5->K6), vT [32M,64M), o_wb [64M,68M)
// d_out (33.55 MB fp32) dead-interval scratch:
//   xn [0,16M) K1->K2 ; uv_wb [16M,24.65M) ; baseb [24.65M,26.25M) ; tables
//   [26.25M,26.5M) ; then qb [0,2M) kb [2M,4M) K3->K4 ; km [4M,12M) K4->K5.
//   All dead before K6 writes d_out.

typedef __bf16 bf16_t;
typedef __bf16 bf16x4 __attribute__((ext_vector_type(4)));
typedef __bf16 bf16x8 __attribute__((ext_vector_type(8)));
typedef float  f32x4  __attribute__((ext_vector_type(4)));

__device__ __forceinline__ void async16(const void* g, void* l) {
  __builtin_amdgcn_global_load_lds(
      (const __attribute__((address_space(1))) void*)g,
      (__attribute__((address_space(3))) void*)l, 16, 0, 0);
}

// ---------------- sentinel (ws guard diagnostics) ----------------
__global__ __launch_bounds__(256) void fill_const(float* __restrict__ out,
                                                  float val, int n) {
  int i = blockIdx.x * 256 + threadIdx.x;
  if (i < n) out[i] = val;
}

// ---------------- K0: rope sin/cos tables ----------------
__global__ void rope_table(float* __restrict__ cosT, float* __restrict__ sinT) {
  int idx = blockIdx.x * 256 + threadIdx.x;   // 512*64
  int n = idx >> 6, j = idx & 63;
  float invf = (float)pow(10000.0, (double)j * (1.0 / 64.0));
  float angf = (float)n * invf;
  cosT[idx] = (float)cos((double)angf);
  sinT[idx] = (float)sin((double)angf);
}

// ---------------- K0b/K0c: fp32 -> bf16 convert ----------------
__global__ __launch_bounds__(256) void cvt_f32_bf16(const float* __restrict__ in,
                                                    bf16_t* __restrict__ out,
                                                    int n4) {
  int i = blockIdx.x * 256 + threadIdx.x;
  if (i < n4) {
    f32x4 v = ((const f32x4*)in)[i];
    bf16x4 o;
    o[0] = (__bf16)v[0]; o[1] = (__bf16)v[1];
    o[2] = (__bf16)v[2]; o[3] = (__bf16)v[3];
    ((bf16x4*)out)[i] = o;
  }
}

// ---------------- K1: layernorm (fp32 in, bf16 out) ----------------
__global__ __launch_bounds__(256) void ln_kernel(const float* __restrict__ x,
                                                 const float* __restrict__ w,
                                                 const float* __restrict__ b,
                                                 bf16_t* __restrict__ xn) {
  int row = blockIdx.x;
  int tid = threadIdx.x;
  f32x4 v = *(const f32x4*)(x + (size_t)row * 1024 + tid * 4);
  float s = v[0] + v[1] + v[2] + v[3];
  float s2 = v[0]*v[0] + v[1]*v[1] + v[2]*v[2] + v[3]*v[3];
  for (int o = 32; o > 0; o >>= 1) {
    s += __shfl_down(s, o);
    s2 += __shfl_down(s2, o);
  }
  __shared__ float ps[4], ps2[4];
  if ((tid & 63) == 0) { ps[tid >> 6] = s; ps2[tid >> 6] = s2; }
  __syncthreads();
  float st = ps[0] + ps[1] + ps[2] + ps[3];
  float st2 = ps2[0] + ps2[1] + ps2[2] + ps2[3];
  float mean = st * (1.f / 1024.f);
  float var = st2 * (1.f / 1024.f) - mean * mean;
  float inv = 1.f / sqrtf(var + 1e-5f);
  bf16x4 o4;
  for (int i = 0; i < 4; i++) {
    float wn = w[tid * 4 + i], bn = b[tid * 4 + i];
    o4[i] = (__bf16)((v[i] - mean) * inv * wn + bn);
  }
  *(bf16x4*)(xn + (size_t)row * 1024 + tid * 4) = o4;
}

// ---------------- K3: gamma/beta + rope -> q, k ----------------
__global__ __launch_bounds__(128) void rope_qk(const bf16_t* __restrict__ baseb,
                                               const float* __restrict__ gamma,
                                               const float* __restrict__ beta,
                                               const float* __restrict__ cosT,
                                               const float* __restrict__ sinT,
                                               bf16_t* __restrict__ q,
                                               bf16_t* __restrict__ k) {
  int m = blockIdx.x;        // b*512 + n
  int n = m & 511;
  int s = threadIdx.x;       // 0..127
  float base = (float)baseb[(size_t)m * 128 + s];
  __shared__ float t[2][128];
  t[0][s] = base * gamma[s] + beta[s];
  t[1][s] = base * gamma[128 + s] + beta[128 + s];
  __syncthreads();
  int j = s & 63;
  float c = cosT[n * 64 + j], sn = sinT[n * 64 + j];
  for (int h = 0; h < 2; h++) {
    float x1 = t[h][j], x2 = t[h][64 + j];
    float r = (s < 64) ? (x1 * c - x2 * sn) : (x2 * c + x1 * sn);
    bf16_t* dst = h == 0 ? q : k;
    dst[(size_t)m * 128 + s] = (__bf16)r;
  }
}

// ---------------- epilogues (NaN-scrub clamps: never fire on legit data) ----
struct EpiUV {   // + uv_b, silu -> u | vT (transposed) | base
  const float* uv_b;
  bf16_t* u;
  bf16_t* vT;      // [16][2048][512]
  bf16_t* baseb;
  __device__ void operator()(int b, int m, int n, float acc) const {
    float xv = acc + uv_b[n];
    // silu via single v_rcp_f32 (R10): '/' expands to div_scale/fmas/fixup
    // (~10+ VALU) without fast-math; rcp is 1 ULP, irrelevant at bf16 out.
    float sv = xv * __builtin_amdgcn_rcpf(1.f + __expf(-xv));
    sv = fminf(fmaxf(sv, -100.f), 100.f);
    if (n < 2048) {
      u[(size_t)m * 2048 + n] = (__bf16)sv;
    } else if (n < 4096) {
      int bb = m >> 9, nseq = m & 511;
      vT[((size_t)bb * 2048 + (n - 2048)) * 512 + nseq] = (__bf16)sv;
    } else {
      baseb[(size_t)m * 128 + (n - 4096)] = (__bf16)sv;
    }
  }
};
struct EpiQK {   // clamp(relu(acc/512 + w_rel[511+j-i]))^2 -> km
  const float* w_rel;
  bf16_t* km;
  __device__ void operator()(int b, int i, int j, float acc) const {
    float bias = w_rel[511 + j - i];
    float t = fmaxf(acc * (1.f / 512.f) + bias, 0.f);
    t = fminf(t, 100.f);
    km[((size_t)b * 512 + i) * 512 + j] = (__bf16)(t * t);
  }
};
struct EpiAttn { // clamp(acc * u) -> out2 (out2 aliases u element-exactly)
  const bf16_t* u;
  bf16_t* out2;
  __device__ void operator()(int b, int i, int e, float acc) const {
    size_t m = (size_t)b * 512 + i;
    float uu = (float)u[m * 2048 + e];
    float r = acc * uu;
    r = fminf(fmaxf(r, -1e6f), 1e6f);
    out2[m * 2048 + e] = (__bf16)r;
  }
};
struct EpiOut {  // clamp(acc + o_b + shortcut) -> fp32 out
  const float* o_b;
  const float* x;
  float* out;
  __device__ void operator()(int b, int m, int d, float acc) const {
    long idx = (long)m * 1024 + d;
    float r = acc + o_b[d] + x[idx];
    r = fminf(fmaxf(r, -1e5f), 1e5f);
    out[idx] = r;
  }
};

// ---------------- templated NT GEMM (dbuf + counted-vmcnt pipeline) --------
// C[m][n] = sum_k A[m][k]*B[n][k]; A,B bf16 K-contiguous. 128x128 tile /
// 256 threads (4 waves 2x2), BK=64, mfma_f32_16x16x32_bf16.
// LDS: 2 buffers x {A 16KB | B 16KB}. Per matrix: 128 rows x 64 bf16;
// k-chunk c of row r at 16B slot c^(r&7) (XOR swizzle; R6 measured 0 bank
// conflicts). Staging addresses precomputed; 8 async16/thread per K-tile.
// Pipeline per iter t: stage(t+1 -> buf^1); vmcnt(8) [tile t's 8 loads
// retired, tile t+1's stay in flight]; s_barrier; compute(buf t&1);
// s_barrier [seals reads before next overwrite].
template <typename Epi>
__global__ __launch_bounds__(256, 2)
void gemm_nt(const bf16_t* __restrict__ A, const bf16_t* __restrict__ Bm,
             int lda, int ldb, int K, long sAz, long sBz, Epi epi) {
  __shared__ __align__(16) char smem[65536];
  const int tid = threadIdx.x;
  const int lane = tid & 63;
  const int wid = tid >> 6;
  const int wm = wid & 1, wn = wid >> 1;
  const int quad = lane >> 4, col16 = lane & 15;
  const int srow = lane >> 3;   // row within 8-row chunk
  const int skc = lane & 7;     // LDS 16B slot within row
  const int bz = blockIdx.z;
  const int tileM = blockIdx.x * 128;
  const int tileN = blockIdx.y * 128;
  const bf16_t* Ab = A + (size_t)bz * sAz;
  const bf16_t* Bb = Bm + (size_t)bz * sBz;
  const int NT = K >> 6;        // K-tiles of 64 (NT >= 2 for all call sites)

  // Hoisted staging geometry: 8 global pointers + 4 LDS offsets, K-invariant.
  const bf16_t* pA[4];
  const bf16_t* pB[4];
  int ldsOff[4];
#pragma unroll
  for (int c4 = 0; c4 < 4; c4++) {
    int ch = c4 * 4 + wid;       // wave-uniform chunk id (16 x 1KB per matrix)
    int row = ch * 8 + srow;
    int kc = skc ^ (row & 7);    // fetch chunk kc so LDS slot skc holds it
    pA[c4] = Ab + (size_t)(tileM + row) * lda + kc * 8;
    pB[c4] = Bb + (size_t)(tileN + row) * ldb + kc * 8;
    ldsOff[c4] = ch * 1024;
  }

  auto stage = [&](int kt, int buf) {   // 8 async16/thread
    char* bA = (char*)smem + buf * 32768;
    char* bB = bA + 16384;
    const size_t ko = (size_t)kt * 64;
#pragma unroll
    for (int c4 = 0; c4 < 4; c4++) {
      async16(pA[c4] + ko, bA + ldsOff[c4]);
      async16(pB[c4] + ko, bB + ldsOff[c4]);
    }
  };

  f32x4 acc[4][4] = {};

  stage(0, 0);
  for (int t = 0; t < NT; t++) {
    if (t + 1 < NT) {
      stage(t + 1, (t + 1) & 1);
      // tile t's 8 loads retired; tile t+1's 8 stay in flight
      asm volatile("s_waitcnt vmcnt(8)" ::: "memory");
    } else {
      asm volatile("s_waitcnt vmcnt(0)" ::: "memory");
    }
    __builtin_amdgcn_s_barrier();     // tile t resident for all waves
    asm volatile("" ::: "memory");

    const char* smA = (const char*)smem + (t & 1) * 32768;
    const char* smB = smA + 16384;
#pragma unroll
    for (int kk = 0; kk < 2; kk++) {
      bf16x8 af[4], bfr[4];
      int jj = kk * 4 + quad;
#pragma unroll
      for (int tt = 0; tt < 4; tt++) {
        int ml = wm * 64 + tt * 16 + col16;
        int nl = wn * 64 + tt * 16 + col16;
        af[tt] = *(const bf16x8*)(smA + (size_t)ml * 128 + ((jj ^ (ml & 7)) * 16));
        bfr[tt] = *(const bf16x8*)(smB + (size_t)nl * 128 + ((jj ^ (nl & 7)) * 16));
      }
#pragma unroll
      for (int mt = 0; mt < 4; mt++)
#pragma unroll
        for (int nt = 0; nt < 4; nt++)
          acc[mt][nt] = __builtin_amdgcn_mfma_f32_16x16x32_bf16(af[mt], bfr[nt], acc[mt][nt], 0, 0, 0);
    }

    if (t + 1 < NT) {
      // seal all waves' reads of buf t&1 before iter t+1 overwrites buf t&1's
      // partner... (next stage targets buf (t+2)&1 = t&1). ds_reads complete
      // before their consuming MFMA issues (hw lgkmcnt), so no waitcnt here.
      asm volatile("" ::: "memory");
      __builtin_amdgcn_s_barrier();
      asm volatile("" ::: "memory");
    }
  }

#pragma unroll
  for (int mt = 0; mt < 4; mt++) {
    int gm = tileM + wm * 64 + mt * 16 + quad * 4;
#pragma unroll
    for (int nt = 0; nt < 4; nt++) {
      int gn = tileN + wn * 64 + nt * 16 + col16;
#pragma unroll
      for (int r = 0; r < 4; r++) epi(bz, gm + r, gn, acc[mt][nt][r]);
    }
  }
}

extern "C" void kernel_launch(void* const* d_in, const int* in_sizes, int n_in,
                              void* d_out, int out_size, void* d_ws, size_t ws_size,
                              hipStream_t stream) {
  const float* x = (const float*)d_in[0];
  const float* ln_w = (const float*)d_in[1];
  const float* ln_b = (const float*)d_in[2];
  const float* uv_w = (const float*)d_in[3];
  const float* uv_b = (const float*)d_in[4];
  const float* gamma = (const float*)d_in[5];
  const float* beta = (const float*)d_in[6];
  const float* o_w = (const float*)d_in[7];
  const float* o_b = (const float*)d_in[8];
  const float* w_rel = (const float*)d_in[9];
  float* out = (float*)d_out;

  const int NOUT = 8388608;
  const size_t WS_NEEDED = 71303168;   // 68 MiB (>=69.4 MiB proven in R5)
  if (ws_size < WS_NEEDED) {
    float wsMiB = (float)(ws_size >> 20);
    fill_const<<<dim3(32768), dim3(256), 0, stream>>>(out, 1000.f + wsMiB, NOUT);
    return;
  }

  // ws: u [0,32M) (out2 alias), vT [32M,64M), o_wb [64M,68M)
  char* ws = (char*)d_ws;
  bf16_t* u = (bf16_t*)(ws + 0);
  bf16_t* out2 = u;
  bf16_t* vT = (bf16_t*)(ws + 33554432);
  bf16_t* o_wb = (bf16_t*)(ws + 67108864);
  // d_out dead-interval scratch (33.55 MB fp32 region):
  char* ob = (char*)d_out;
  bf16_t* xn = (bf16_t*)ob;                       // [0, 16,777,216)
  bf16_t* uv_wb = (bf16_t*)(ob + 16777216);       // [16,777,216, 25,427,968)
  bf16_t* baseb = (bf16_t*)(ob + 25427968);       // [25,427,968, 27,525,120)
  float* cosT = (float*)(ob + 27525120);          // [27,525,120, 27,656,192)
  float* sinT = (float*)(ob + 27656192);          // [27,656,192, 27,787,264)
  bf16_t* qb = (bf16_t*)ob;                       // [0, 2M)   K3->K4
  bf16_t* kb = (bf16_t*)(ob + 2097152);           // [2M, 4M)  K3->K4
  bf16_t* km = (bf16_t*)(ob + 4194304);           // [4M, 12M) K4->K5

  rope_table<<<dim3(128), dim3(256), 0, stream>>>(cosT, sinT);
  cvt_f32_bf16<<<dim3(4224), dim3(256), 0, stream>>>(uv_w, uv_wb, 1081344);
  cvt_f32_bf16<<<dim3(2048), dim3(256), 0, stream>>>(o_w, o_wb, 524288);
  ln_kernel<<<dim3(8192), dim3(256), 0, stream>>>(x, ln_w, ln_b, xn);
  // K2: silu(xn @ uv_wb^T + uv_b) -> u | vT | base: M=8192, N=4224, K=1024
  gemm_nt<<<dim3(64, 33, 1), dim3(256), 0, stream>>>(
      xn, uv_wb, 1024, 1024, 1024, 0L, 0L, EpiUV{uv_b, u, vT, baseb});
  rope_qk<<<dim3(8192), dim3(128), 0, stream>>>(baseb, gamma, beta, cosT, sinT, qb, kb);
  // K4: km = relu(q@k^T/512 + bias)^2: per batch M=N=512, K=128
  gemm_nt<<<dim3(4, 4, 16), dim3(256), 0, stream>>>(
      qb, kb, 128, 128, 128, (long)512 * 128, (long)512 * 128, EpiQK{w_rel, km});
  // K5: out2 = u * (km @ v): per batch M=512, N=2048, K=512
  gemm_nt<<<dim3(4, 16, 16), dim3(256), 0, stream>>>(
      km, vT, 512, 512, 512, (long)512 * 512, (long)2048 * 512, EpiAttn{u, out2});
  // K6: out = out2 @ o_wb^T + o_b + x: M=8192, N=1024, K=2048
  gemm_nt<<<dim3(64, 8, 1), dim3(256), 0, stream>>>(
      out2, o_wb, 2048, 2048, 2048, 0L, 0L, EpiOut{o_b, x, out});
}

// Round 5
// 335.036 us; speedup vs baseline: 1.0353x; 1.0353x over previous
//
#include <hip/hip_runtime.h>
#include <hip/hip_bf16.h>

// GateAttentionUnit. B=16, N=512, D=1024, E=2048, S=128, F=2E+S=4224.
// CONFIRMED: all 10 inputs fp32, output fp32. Internal compute bf16 MFMA.
//
// Pipeline:
//   K0 rope_table: cos/sin[512][64] fp32 -> d_out scratch
//   K0b cvt uv_w -> bf16 (d_out scratch); K0c cvt o_w -> bf16 (ws)
//   K1 ln:         x -> xn bf16 (d_out scratch)                    [8192 x 1024]
//   K2 gemm<8,EpiUV>: silu(xn @ uv_wb^T + uv_b) -> u | vT | base   [8192 x 4224]
//   K3 rope_qk:    q,k = rope(base*gamma+beta) (d_out scratch)     [8192 x 128]
//   K4 gemm<4,EpiQK>:   km = relu(q@k^T/512 + relpos)^2 (d_out)    [16][512][512]
//   K5 gemm<8,EpiAttn>: out2 = u * (km @ vT^T), out2 aliases u     [8192 x 2048]
//   K6 gemm<4,EpiOut>:  out = out2 @ o_wb^T + o_b + x  (fp32 out)  [8192 x 1024]
//
// R11 -> R12: (a) sync structure REVERTED to the R10-proven single-buffer
// __syncthreads loop (R11's counted-vmcnt regressed: 64KB LDS halved
// residency 5->2 blocks/CU, and hipcc re-drains vmcnt at barriers anyway --
// third failed sync edit; off the table now). (b) NEW: tile height templated
// (MFR m-fragments/wave): K2/K5 use 256x128 blocks (wave = 128x64, acc[8][4])
// -- LDS bytes/FLOP drop 25% (0.046->0.034) and MFMA-per-barrier doubles.
// Rationale: per-CU LDS pipe (~85B/cyc) serves ~1030 cyc/K-tile vs 155 cyc
// MFMA -- LDS serialization, shared by all waves, is why MfmaUtil pins at
// ~27% and why TLP/pipelining can't fix it. Tile-size change, not sync edit.
// (c) epilogue takes f32x4 (4 consecutive m): vT transpose-store becomes one
// 8B store per call (was 4 scattered 2B stores; R10 WRITE_SIZE 95MB vs 69MB
// ideal), uv_b/o_b loads hoisted 4x.
//
// ws (68 MiB; >=69.4 MiB proven available in R5):
//   u [0,32M) (K2->K5; out2 alias K5->K6), vT [32M,64M), o_wb [64M,68M)
// d_out (33.55 MB fp32) dead-interval scratch:
//   xn [0,16M) K1->K2 ; uv_wb [16M,24.65M) ; baseb [24.65M,26.25M) ; tables
//   [26.25M,26.5M) ; then qb [0,2M) kb [2M,4M) K3->K4 ; km [4M,12M) K4->K5.
//   All dead before K6 writes d_out.

typedef __bf16 bf16_t;
typedef __bf16 bf16x4 __attribute__((ext_vector_type(4)));
typedef __bf16 bf16x8 __attribute__((ext_vector_type(8)));
typedef float  f32x4  __attribute__((ext_vector_type(4)));

__device__ __forceinline__ void async16(const void* g, void* l) {
  __builtin_amdgcn_global_load_lds(
      (const __attribute__((address_space(1))) void*)g,
      (__attribute__((address_space(3))) void*)l, 16, 0, 0);
}

// ---------------- sentinel (ws guard diagnostics) ----------------
__global__ __launch_bounds__(256) void fill_const(float* __restrict__ out,
                                                  float val, int n) {
  int i = blockIdx.x * 256 + threadIdx.x;
  if (i < n) out[i] = val;
}

// ---------------- K0: rope sin/cos tables ----------------
__global__ void rope_table(float* __restrict__ cosT, float* __restrict__ sinT) {
  int idx = blockIdx.x * 256 + threadIdx.x;   // 512*64
  int n = idx >> 6, j = idx & 63;
  float invf = (float)pow(10000.0, (double)j * (1.0 / 64.0));
  float angf = (float)n * invf;
  cosT[idx] = (float)cos((double)angf);
  sinT[idx] = (float)sin((double)angf);
}

// ---------------- K0b/K0c: fp32 -> bf16 convert ----------------
__global__ __launch_bounds__(256) void cvt_f32_bf16(const float* __restrict__ in,
                                                    bf16_t* __restrict__ out,
                                                    int n4) {
  int i = blockIdx.x * 256 + threadIdx.x;
  if (i < n4) {
    f32x4 v = ((const f32x4*)in)[i];
    bf16x4 o;
    o[0] = (__bf16)v[0]; o[1] = (__bf16)v[1];
    o[2] = (__bf16)v[2]; o[3] = (__bf16)v[3];
    ((bf16x4*)out)[i] = o;
  }
}

// ---------------- K1: layernorm (fp32 in, bf16 out) ----------------
__global__ __launch_bounds__(256) void ln_kernel(const float* __restrict__ x,
                                                 const float* __restrict__ w,
                                                 const float* __restrict__ b,
                                                 bf16_t* __restrict__ xn) {
  int row = blockIdx.x;
  int tid = threadIdx.x;
  f32x4 v = *(const f32x4*)(x + (size_t)row * 1024 + tid * 4);
  float s = v[0] + v[1] + v[2] + v[3];
  float s2 = v[0]*v[0] + v[1]*v[1] + v[2]*v[2] + v[3]*v[3];
  for (int o = 32; o > 0; o >>= 1) {
    s += __shfl_down(s, o);
    s2 += __shfl_down(s2, o);
  }
  __shared__ float ps[4], ps2[4];
  if ((tid & 63) == 0) { ps[tid >> 6] = s; ps2[tid >> 6] = s2; }
  __syncthreads();
  float st = ps[0] + ps[1] + ps[2] + ps[3];
  float st2 = ps2[0] + ps2[1] + ps2[2] + ps2[3];
  float mean = st * (1.f / 1024.f);
  float var = st2 * (1.f / 1024.f) - mean * mean;
  float inv = 1.f / sqrtf(var + 1e-5f);
  bf16x4 o4;
  for (int i = 0; i < 4; i++) {
    float wn = w[tid * 4 + i], bn = b[tid * 4 + i];
    o4[i] = (__bf16)((v[i] - mean) * inv * wn + bn);
  }
  *(bf16x4*)(xn + (size_t)row * 1024 + tid * 4) = o4;
}

// ---------------- K3: gamma/beta + rope -> q, k ----------------
__global__ __launch_bounds__(128) void rope_qk(const bf16_t* __restrict__ baseb,
                                               const float* __restrict__ gamma,
                                               const float* __restrict__ beta,
                                               const float* __restrict__ cosT,
                                               const float* __restrict__ sinT,
                                               bf16_t* __restrict__ q,
                                               bf16_t* __restrict__ k) {
  int m = blockIdx.x;        // b*512 + n
  int n = m & 511;
  int s = threadIdx.x;       // 0..127
  float base = (float)baseb[(size_t)m * 128 + s];
  __shared__ float t[2][128];
  t[0][s] = base * gamma[s] + beta[s];
  t[1][s] = base * gamma[128 + s] + beta[128 + s];
  __syncthreads();
  int j = s & 63;
  float c = cosT[n * 64 + j], sn = sinT[n * 64 + j];
  for (int h = 0; h < 2; h++) {
    float x1 = t[h][j], x2 = t[h][64 + j];
    float r = (s < 64) ? (x1 * c - x2 * sn) : (x2 * c + x1 * sn);
    bf16_t* dst = h == 0 ? q : k;
    dst[(size_t)m * 128 + s] = (__bf16)r;
  }
}

// ------- epilogues: f32x4 = C rows m0..m0+3, col n. NaN-scrub clamps. ------
struct EpiUV {   // + uv_b, silu -> u | vT (transposed) | base
  const float* uv_b;
  bf16_t* u;
  bf16_t* vT;      // [16][2048][512]
  bf16_t* baseb;
  __device__ void operator()(int b, int m0, int n, f32x4 a4) const {
    float bn = uv_b[n];
    bf16_t s[4];
#pragma unroll
    for (int r = 0; r < 4; r++) {
      float xv = a4[r] + bn;
      // silu via v_rcp_f32 (R10): '/' expands to div_scale/fmas/fixup.
      float sv = xv * __builtin_amdgcn_rcpf(1.f + __expf(-xv));
      sv = fminf(fmaxf(sv, -100.f), 100.f);
      s[r] = (__bf16)sv;
    }
    if (n < 2048) {
#pragma unroll
      for (int r = 0; r < 4; r++) u[(size_t)(m0 + r) * 2048 + n] = s[r];
    } else if (n < 4096) {
      // transpose store: 4 consecutive nseq for fixed e -> one 8B store
      int bb = m0 >> 9, ns = m0 & 511;
      bf16x4 p; p[0] = s[0]; p[1] = s[1]; p[2] = s[2]; p[3] = s[3];
      *(bf16x4*)(vT + ((size_t)bb * 2048 + (n - 2048)) * 512 + ns) = p;
    } else {
#pragma unroll
      for (int r = 0; r < 4; r++)
        baseb[(size_t)(m0 + r) * 128 + (n - 4096)] = s[r];
    }
  }
};
struct EpiQK {   // clamp(relu(acc/512 + w_rel[511+j-i]))^2 -> km
  const float* w_rel;
  bf16_t* km;
  __device__ void operator()(int b, int i0, int j, f32x4 a4) const {
#pragma unroll
    for (int r = 0; r < 4; r++) {
      float bias = w_rel[511 + j - (i0 + r)];
      float t = fmaxf(a4[r] * (1.f / 512.f) + bias, 0.f);
      t = fminf(t, 100.f);
      km[((size_t)b * 512 + i0 + r) * 512 + j] = (__bf16)(t * t);
    }
  }
};
struct EpiAttn { // clamp(acc * u) -> out2 (out2 aliases u element-exactly)
  const bf16_t* u;
  bf16_t* out2;
  __device__ void operator()(int b, int i0, int e, f32x4 a4) const {
#pragma unroll
    for (int r = 0; r < 4; r++) {
      size_t m = (size_t)b * 512 + i0 + r;
      float uu = (float)u[m * 2048 + e];
      float rr = a4[r] * uu;
      rr = fminf(fmaxf(rr, -1e6f), 1e6f);
      out2[m * 2048 + e] = (__bf16)rr;
    }
  }
};
struct EpiOut {  // clamp(acc + o_b + shortcut) -> fp32 out
  const float* o_b;
  const float* x;
  float* out;
  __device__ void operator()(int b, int m0, int d, f32x4 a4) const {
    float ob = o_b[d];
#pragma unroll
    for (int r = 0; r < 4; r++) {
      long idx = (long)(m0 + r) * 1024 + d;
      float rr = a4[r] + ob + x[idx];
      rr = fminf(fmaxf(rr, -1e5f), 1e5f);
      out[idx] = rr;
    }
  }
};

// ---------------- templated NT GEMM (async-staged, XOR-swizzled LDS) -------
// C[m][n] = sum_k A[m][k]*B[n][k]; A,B bf16 K-contiguous. Block tile
// (MFR*32) x 128, 256 threads (4 waves 2x2); wave computes (MFR*16) x 64.
// MFR=4: 128^2 block (proven R6/R10 config). MFR=8: 256x128 block -- 25%
// less LDS traffic per FLOP, 2x MFMA per barrier (R12).
// LDS: A = MROWS x 64 bf16, B = 128 x 64 bf16, single-buffered; k-chunk c of
// row r at 16B slot c^(r&7) (XOR swizzle; R6 measured 0 bank conflicts).
// Sync structure: stage -> __syncthreads -> compute -> __syncthreads
// (PROVEN; counted-vmcnt variants regressed in R8/R9/R11 -- do not re-edit).
template <int MFR, typename Epi>
__global__ __launch_bounds__(256, 2)
void gemm_nt(const bf16_t* __restrict__ A, const bf16_t* __restrict__ Bm,
             int lda, int ldb, int K, long sAz, long sBz, Epi epi) {
  constexpr int MROWS = MFR * 32;
  __shared__ __align__(16) char smem[MROWS * 128 + 16384];
  const int tid = threadIdx.x;
  const int lane = tid & 63;
  const int wid = tid >> 6;
  const int wm = wid & 1, wn = wid >> 1;
  const int quad = lane >> 4, col16 = lane & 15;
  const int srow = lane >> 3;   // row within 8-row chunk
  const int skc = lane & 7;     // LDS 16B slot within row
  const int bz = blockIdx.z;
  const int tileM = blockIdx.x * MROWS;
  const int tileN = blockIdx.y * 128;
  const bf16_t* Ab = A + (size_t)bz * sAz;
  const bf16_t* Bb = Bm + (size_t)bz * sBz;

  // Hoisted staging element-offsets (32-bit: max index ~16.8M, fits).
  unsigned oA[MFR], oB[4];
#pragma unroll
  for (int c4 = 0; c4 < MFR; c4++) {
    int ch = c4 * 4 + wid;       // wave-uniform 1KB chunk id
    int row = ch * 8 + srow;
    int kc = skc ^ (row & 7);    // fetch chunk kc so LDS slot skc holds it
    oA[c4] = (unsigned)((tileM + row) * lda + kc * 8);
  }
#pragma unroll
  for (int c4 = 0; c4 < 4; c4++) {
    int ch = c4 * 4 + wid;
    int row = ch * 8 + srow;
    int kc = skc ^ (row & 7);
    oB[c4] = (unsigned)((tileN + row) * ldb + kc * 8);
  }

  f32x4 acc[MFR][4] = {};

  for (int k0 = 0; k0 < K; k0 += 64) {
#pragma unroll
    for (int c4 = 0; c4 < MFR; c4++)
      async16(Ab + oA[c4] + k0, smem + (c4 * 4 + wid) * 1024);
#pragma unroll
    for (int c4 = 0; c4 < 4; c4++)
      async16(Bb + oB[c4] + k0, smem + MROWS * 128 + (c4 * 4 + wid) * 1024);
    __syncthreads();

    const char* smA = (const char*)smem;
    const char* smB = smA + MROWS * 128;
#pragma unroll
    for (int kk = 0; kk < 2; kk++) {
      bf16x8 af[MFR], bfr[4];
      int jj = kk * 4 + quad;
#pragma unroll
      for (int tt = 0; tt < MFR; tt++) {
        int ml = wm * (MFR * 16) + tt * 16 + col16;
        af[tt] = *(const bf16x8*)(smA + (size_t)ml * 128 + ((jj ^ (ml & 7)) * 16));
      }
#pragma unroll
      for (int tt = 0; tt < 4; tt++) {
        int nl = wn * 64 + tt * 16 + col16;
        bfr[tt] = *(const bf16x8*)(smB + (size_t)nl * 128 + ((jj ^ (nl & 7)) * 16));
      }
#pragma unroll
      for (int mt = 0; mt < MFR; mt++)
#pragma unroll
        for (int nt = 0; nt < 4; nt++)
          acc[mt][nt] = __builtin_amdgcn_mfma_f32_16x16x32_bf16(af[mt], bfr[nt], acc[mt][nt], 0, 0, 0);
    }
    __syncthreads();
  }

#pragma unroll
  for (int mt = 0; mt < MFR; mt++) {
    int gm = tileM + wm * (MFR * 16) + mt * 16 + quad * 4;
#pragma unroll
    for (int nt = 0; nt < 4; nt++) {
      int gn = tileN + wn * 64 + nt * 16 + col16;
      epi(bz, gm, gn, acc[mt][nt]);
    }
  }
}

extern "C" void kernel_launch(void* const* d_in, const int* in_sizes, int n_in,
                              void* d_out, int out_size, void* d_ws, size_t ws_size,
                              hipStream_t stream) {
  const float* x = (const float*)d_in[0];
  const float* ln_w = (const float*)d_in[1];
  const float* ln_b = (const float*)d_in[2];
  const float* uv_w = (const float*)d_in[3];
  const float* uv_b = (const float*)d_in[4];
  const float* gamma = (const float*)d_in[5];
  const float* beta = (const float*)d_in[6];
  const float* o_w = (const float*)d_in[7];
  const float* o_b = (const float*)d_in[8];
  const float* w_rel = (const float*)d_in[9];
  float* out = (float*)d_out;

  const int NOUT = 8388608;
  const size_t WS_NEEDED = 71303168;   // 68 MiB (>=69.4 MiB proven in R5)
  if (ws_size < WS_NEEDED) {
    float wsMiB = (float)(ws_size >> 20);
    fill_const<<<dim3(32768), dim3(256), 0, stream>>>(out, 1000.f + wsMiB, NOUT);
    return;
  }

  // ws: u [0,32M) (out2 alias), vT [32M,64M), o_wb [64M,68M)
  char* ws = (char*)d_ws;
  bf16_t* u = (bf16_t*)(ws + 0);
  bf16_t* out2 = u;
  bf16_t* vT = (bf16_t*)(ws + 33554432);
  bf16_t* o_wb = (bf16_t*)(ws + 67108864);
  // d_out dead-interval scratch (33.55 MB fp32 region):
  char* ob = (char*)d_out;
  bf16_t* xn = (bf16_t*)ob;                       // [0, 16,777,216)
  bf16_t* uv_wb = (bf16_t*)(ob + 16777216);       // [16,777,216, 25,427,968)
  bf16_t* baseb = (bf16_t*)(ob + 25427968);       // [25,427,968, 27,525,120)
  float* cosT = (float*)(ob + 27525120);          // [27,525,120, 27,656,192)
  float* sinT = (float*)(ob + 27656192);          // [27,656,192, 27,787,264)
  bf16_t* qb = (bf16_t*)ob;                       // [0, 2M)   K3->K4
  bf16_t* kb = (bf16_t*)(ob + 2097152);           // [2M, 4M)  K3->K4
  bf16_t* km = (bf16_t*)(ob + 4194304);           // [4M, 12M) K4->K5

  rope_table<<<dim3(128), dim3(256), 0, stream>>>(cosT, sinT);
  cvt_f32_bf16<<<dim3(4224), dim3(256), 0, stream>>>(uv_w, uv_wb, 1081344);
  cvt_f32_bf16<<<dim3(2048), dim3(256), 0, stream>>>(o_w, o_wb, 524288);
  ln_kernel<<<dim3(8192), dim3(256), 0, stream>>>(x, ln_w, ln_b, xn);
  // K2: silu(xn @ uv_wb^T + uv_b) -> u | vT | base: M=8192, N=4224, K=1024
  gemm_nt<8><<<dim3(32, 33, 1), dim3(256), 0, stream>>>(
      xn, uv_wb, 1024, 1024, 1024, 0L, 0L, EpiUV{uv_b, u, vT, baseb});
  rope_qk<<<dim3(8192), dim3(128), 0, stream>>>(baseb, gamma, beta, cosT, sinT, qb, kb);
  // K4: km = relu(q@k^T/512 + bias)^2: per batch M=N=512, K=128
  gemm_nt<4><<<dim3(4, 4, 16), dim3(256), 0, stream>>>(
      qb, kb, 128, 128, 128, (long)512 * 128, (long)512 * 128, EpiQK{w_rel, km});
  // K5: out2 = u * (km @ v): per batch M=512, N=2048, K=512
  gemm_nt<8><<<dim3(2, 16, 16), dim3(256), 0, stream>>>(
      km, vT, 512, 512, 512, (long)512 * 512, (long)2048 * 512, EpiAttn{u, out2});
  // K6: out = out2 @ o_wb^T + o_b + x: M=8192, N=1024, K=2048
  gemm_nt<4><<<dim3(64, 8, 1), dim3(256), 0, stream>>>(
      out2, o_wb, 2048, 2048, 2048, 0L, 0L, EpiOut{o_b, x, out});
}

// Round 6
// 330.827 us; speedup vs baseline: 1.0484x; 1.0127x over previous
//
#include <hip/hip_runtime.h>
#include <hip/hip_bf16.h>

// GateAttentionUnit. B=16, N=512, D=1024, E=2048, S=128, F=2E+S=4224.
// CONFIRMED: all 10 inputs fp32, output fp32. Internal compute bf16 MFMA.
//
// Pipeline:
//   K0 rope_table: cos/sin[512][64] fp32 -> d_out scratch
//   K0b cvt uv_w -> bf16 (d_out scratch); K0c cvt o_w -> bf16 (ws)
//   K1 ln:         x -> xn bf16 (d_out scratch)                    [8192 x 1024]
//   K2 gemm<4,EpiUV>: silu(xn @ uv_wb^T + uv_b) -> u | vT | base   [8192 x 4224]
//   K3 rope_qk:    q,k = rope(base*gamma+beta) (d_out scratch)     [8192 x 128]
//   K4 gemm<4,EpiQK>:   km = relu(q@k^T/512 + relpos)^2 (d_out)    [16][512][512]
//   K5 gemm<8,EpiAttn>: out2 = u * (km @ vT^T), out2 aliases u     [8192 x 2048]
//   K6 gemm<4,EpiOut>:  out = out2 @ o_wb^T + o_b + x  (fp32 out)  [8192 x 1024]
//
// R12 -> R13: latency-hiding WITHIN the __syncthreads idiom. R12 evidence:
// cutting LDS bytes/FLOP 25% (MFR=8) did NOT help K2 (110->115.5, occupancy
// halved) -> LDS BW is not binding; exposed load latency is (m97 structure
// stages immediately before the drain). New loop: BK=32, TWO 16KB buffers
// (32KB total -- same LDS/occupancy as proven R10), stage(t+1) issued right
// AFTER the barrier, before compute(t): the vmcnt(0) drain hipcc emits at
// __syncthreads now waits on loads issued one full compute phase earlier.
// No raw barriers, no counted vmcnt (those failed 3x: R8/R9/R11). Barrier
// count per K unchanged. K2 back to MFR=4 (R12: MFR=8 lost TLP on K2).
// K5 keeps MFR=8 (R12: ~9us win; grid 512 = 2/CU exact).
// Race-freedom: stage(t+1) writes buf^1, iter t reads buf (disjoint);
// iter-t ds_reads lgkmcnt-drained at barrier t+1 before stage(t+2)
// overwrites buf. f32x4 epilogues (R12: WRITE_SIZE 95->72, keep).
//
// ws (68 MiB; >=69.4 MiB proven available in R5):
//   u [0,32M) (K2->K5; out2 alias K5->K6), vT [32M,64M), o_wb [64M,68M)
// d_out (33.55 MB fp32) dead-interval scratch:
//   xn [0,16M) K1->K2 ; uv_wb [16M,24.65M) ; baseb [24.65M,26.25M) ; tables
//   [26.25M,26.5M) ; then qb [0,2M) kb [2M,4M) K3->K4 ; km [4M,12M) K4->K5.
//   All dead before K6 writes d_out.

typedef __bf16 bf16_t;
typedef __bf16 bf16x4 __attribute__((ext_vector_type(4)));
typedef __bf16 bf16x8 __attribute__((ext_vector_type(8)));
typedef float  f32x4  __attribute__((ext_vector_type(4)));

__device__ __forceinline__ void async16(const void* g, void* l) {
  __builtin_amdgcn_global_load_lds(
      (const __attribute__((address_space(1))) void*)g,
      (__attribute__((address_space(3))) void*)l, 16, 0, 0);
}

// ---------------- sentinel (ws guard diagnostics) ----------------
__global__ __launch_bounds__(256) void fill_const(float* __restrict__ out,
                                                  float val, int n) {
  int i = blockIdx.x * 256 + threadIdx.x;
  if (i < n) out[i] = val;
}

// ---------------- K0: rope sin/cos tables ----------------
__global__ void rope_table(float* __restrict__ cosT, float* __restrict__ sinT) {
  int idx = blockIdx.x * 256 + threadIdx.x;   // 512*64
  int n = idx >> 6, j = idx & 63;
  float invf = (float)pow(10000.0, (double)j * (1.0 / 64.0));
  float angf = (float)n * invf;
  cosT[idx] = (float)cos((double)angf);
  sinT[idx] = (float)sin((double)angf);
}

// ---------------- K0b/K0c: fp32 -> bf16 convert ----------------
__global__ __launch_bounds__(256) void cvt_f32_bf16(const float* __restrict__ in,
                                                    bf16_t* __restrict__ out,
                                                    int n4) {
  int i = blockIdx.x * 256 + threadIdx.x;
  if (i < n4) {
    f32x4 v = ((const f32x4*)in)[i];
    bf16x4 o;
    o[0] = (__bf16)v[0]; o[1] = (__bf16)v[1];
    o[2] = (__bf16)v[2]; o[3] = (__bf16)v[3];
    ((bf16x4*)out)[i] = o;
  }
}

// ---------------- K1: layernorm (fp32 in, bf16 out) ----------------
__global__ __launch_bounds__(256) void ln_kernel(const float* __restrict__ x,
                                                 const float* __restrict__ w,
                                                 const float* __restrict__ b,
                                                 bf16_t* __restrict__ xn) {
  int row = blockIdx.x;
  int tid = threadIdx.x;
  f32x4 v = *(const f32x4*)(x + (size_t)row * 1024 + tid * 4);
  float s = v[0] + v[1] + v[2] + v[3];
  float s2 = v[0]*v[0] + v[1]*v[1] + v[2]*v[2] + v[3]*v[3];
  for (int o = 32; o > 0; o >>= 1) {
    s += __shfl_down(s, o);
    s2 += __shfl_down(s2, o);
  }
  __shared__ float ps[4], ps2[4];
  if ((tid & 63) == 0) { ps[tid >> 6] = s; ps2[tid >> 6] = s2; }
  __syncthreads();
  float st = ps[0] + ps[1] + ps[2] + ps[3];
  float st2 = ps2[0] + ps2[1] + ps2[2] + ps2[3];
  float mean = st * (1.f / 1024.f);
  float var = st2 * (1.f / 1024.f) - mean * mean;
  float inv = 1.f / sqrtf(var + 1e-5f);
  bf16x4 o4;
  for (int i = 0; i < 4; i++) {
    float wn = w[tid * 4 + i], bn = b[tid * 4 + i];
    o4[i] = (__bf16)((v[i] - mean) * inv * wn + bn);
  }
  *(bf16x4*)(xn + (size_t)row * 1024 + tid * 4) = o4;
}

// ---------------- K3: gamma/beta + rope -> q, k ----------------
__global__ __launch_bounds__(128) void rope_qk(const bf16_t* __restrict__ baseb,
                                               const float* __restrict__ gamma,
                                               const float* __restrict__ beta,
                                               const float* __restrict__ cosT,
                                               const float* __restrict__ sinT,
                                               bf16_t* __restrict__ q,
                                               bf16_t* __restrict__ k) {
  int m = blockIdx.x;        // b*512 + n
  int n = m & 511;
  int s = threadIdx.x;       // 0..127
  float base = (float)baseb[(size_t)m * 128 + s];
  __shared__ float t[2][128];
  t[0][s] = base * gamma[s] + beta[s];
  t[1][s] = base * gamma[128 + s] + beta[128 + s];
  __syncthreads();
  int j = s & 63;
  float c = cosT[n * 64 + j], sn = sinT[n * 64 + j];
  for (int h = 0; h < 2; h++) {
    float x1 = t[h][j], x2 = t[h][64 + j];
    float r = (s < 64) ? (x1 * c - x2 * sn) : (x2 * c + x1 * sn);
    bf16_t* dst = h == 0 ? q : k;
    dst[(size_t)m * 128 + s] = (__bf16)r;
  }
}

// ------- epilogues: f32x4 = C rows m0..m0+3, col n. NaN-scrub clamps. ------
struct EpiUV {   // + uv_b, silu -> u | vT (transposed) | base
  const float* uv_b;
  bf16_t* u;
  bf16_t* vT;      // [16][2048][512]
  bf16_t* baseb;
  __device__ void operator()(int b, int m0, int n, f32x4 a4) const {
    float bn = uv_b[n];
    bf16_t s[4];
#pragma unroll
    for (int r = 0; r < 4; r++) {
      float xv = a4[r] + bn;
      // silu via v_rcp_f32 (R10): '/' expands to div_scale/fmas/fixup.
      float sv = xv * __builtin_amdgcn_rcpf(1.f + __expf(-xv));
      sv = fminf(fmaxf(sv, -100.f), 100.f);
      s[r] = (__bf16)sv;
    }
    if (n < 2048) {
#pragma unroll
      for (int r = 0; r < 4; r++) u[(size_t)(m0 + r) * 2048 + n] = s[r];
    } else if (n < 4096) {
      // transpose store: 4 consecutive nseq for fixed e -> one 8B store
      int bb = m0 >> 9, ns = m0 & 511;
      bf16x4 p; p[0] = s[0]; p[1] = s[1]; p[2] = s[2]; p[3] = s[3];
      *(bf16x4*)(vT + ((size_t)bb * 2048 + (n - 2048)) * 512 + ns) = p;
    } else {
#pragma unroll
      for (int r = 0; r < 4; r++)
        baseb[(size_t)(m0 + r) * 128 + (n - 4096)] = s[r];
    }
  }
};
struct EpiQK {   // clamp(relu(acc/512 + w_rel[511+j-i]))^2 -> km
  const float* w_rel;
  bf16_t* km;
  __device__ void operator()(int b, int i0, int j, f32x4 a4) const {
#pragma unroll
    for (int r = 0; r < 4; r++) {
      float bias = w_rel[511 + j - (i0 + r)];
      float t = fmaxf(a4[r] * (1.f / 512.f) + bias, 0.f);
      t = fminf(t, 100.f);
      km[((size_t)b * 512 + i0 + r) * 512 + j] = (__bf16)(t * t);
    }
  }
};
struct EpiAttn { // clamp(acc * u) -> out2 (out2 aliases u element-exactly)
  const bf16_t* u;
  bf16_t* out2;
  __device__ void operator()(int b, int i0, int e, f32x4 a4) const {
#pragma unroll
    for (int r = 0; r < 4; r++) {
      size_t m = (size_t)b * 512 + i0 + r;
      float uu = (float)u[m * 2048 + e];
      float rr = a4[r] * uu;
      rr = fminf(fmaxf(rr, -1e6f), 1e6f);
      out2[m * 2048 + e] = (__bf16)rr;
    }
  }
};
struct EpiOut {  // clamp(acc + o_b + shortcut) -> fp32 out
  const float* o_b;
  const float* x;
  float* out;
  __device__ void operator()(int b, int m0, int d, f32x4 a4) const {
    float ob = o_b[d];
#pragma unroll
    for (int r = 0; r < 4; r++) {
      long idx = (long)(m0 + r) * 1024 + d;
      float rr = a4[r] + ob + x[idx];
      rr = fminf(fmaxf(rr, -1e5f), 1e5f);
      out[idx] = rr;
    }
  }
};

// -------- templated NT GEMM (BK=32 dbuf, stage-after-barrier pipeline) -----
// C[m][n] = sum_k A[m][k]*B[n][k]; A,B bf16 K-contiguous. Block tile
// (MFR*32) x 128, 256 threads (4 waves 2x2); wave computes (MFR*16) x 64.
// BK=32. LDS: 2 buffers x {A MROWS*64B | B 8KB}. MFR=4: 32KB total (same as
// proven R10), MFR=8: 48KB.
// Layout per matrix: 128B lines = 2 rows x 32 bf16. Within line L, 16B slot
// s holds source chunk g = s^(L&7) (row 2L+(g>>2), k-chunk g&3). Fragment
// read (row ml, k-chunk quad): byte = L*128 + ((g^(L&7))*16), L=ml>>1,
// g=(ml&1)*4+quad -> 16 lanes cover all 8 slots exactly twice = 2-way bank
// alias (free, same class as R6's verified-0-conflict layout).
// Loop: __syncthreads (drains tile-t loads, issued ONE compute phase ago);
// stage(t+1 -> buf^1); compute(buf). One barrier per K-32 (same count as
// R10's 2 per K-64). No raw barriers / counted vmcnt (failed 3x).
template <int MFR, typename Epi>
__global__ __launch_bounds__(256, 2)
void gemm_nt(const bf16_t* __restrict__ A, const bf16_t* __restrict__ Bm,
             int lda, int ldb, int K, long sAz, long sBz, Epi epi) {
  constexpr int MROWS = MFR * 32;
  constexpr int ABYTES = MROWS * 64;      // A region per buffer
  constexpr int BUFB = ABYTES + 8192;     // + B region (128 rows x 64B)
  constexpr int NA = MROWS / 64;          // A staging iters (1KB blocks /4 waves)
  __shared__ __align__(16) char smem[2 * BUFB];
  const int tid = threadIdx.x;
  const int lane = tid & 63;
  const int wid = tid >> 6;
  const int wm = wid & 1, wn = wid >> 1;
  const int quad = lane >> 4, col16 = lane & 15;
  const int bz = blockIdx.z;
  const int tileM = blockIdx.x * MROWS;
  const int tileN = blockIdx.y * 128;
  const bf16_t* Ab = A + (size_t)bz * sAz;
  const bf16_t* Bb = Bm + (size_t)bz * sBz;
  const int NT = K >> 5;                  // K-tiles of 32

  // Staging geometry: chunk c = u*64 + lane (u = i*4+wid wave-uniform 1KB id);
  // line L = c>>3, slot s = c&7; source g = s^(L&7) -> g is u-independent:
  // g = (lane&7) ^ ((lane>>3)&7). Source row = u*16 + 2*(lane>>3) + (g>>2).
  const int g = (lane & 7) ^ ((lane >> 3) & 7);
  const int rowb = 2 * (lane >> 3) + (g >> 2);
  const int kcb = (g & 3) * 8;            // element offset within row
  unsigned oA[NA], oB[2];
#pragma unroll
  for (int i = 0; i < NA; i++) {
    int u = i * 4 + wid;
    oA[i] = (unsigned)((tileM + u * 16 + rowb) * lda + kcb);
  }
#pragma unroll
  for (int i = 0; i < 2; i++) {
    int u = i * 4 + wid;
    oB[i] = (unsigned)((tileN + u * 16 + rowb) * ldb + kcb);
  }

  // Fragment byte offsets (row ml/nl, k-chunk quad).
  int offA[MFR], offB[4];
#pragma unroll
  for (int mt = 0; mt < MFR; mt++) {
    int ml = wm * (MFR * 16) + mt * 16 + col16;
    int L = ml >> 1, gg = (ml & 1) * 4 + quad;
    offA[mt] = L * 128 + ((gg ^ (L & 7)) * 16);
  }
#pragma unroll
  for (int nt = 0; nt < 4; nt++) {
    int nl = wn * 64 + nt * 16 + col16;
    int L = nl >> 1, gg = (nl & 1) * 4 + quad;
    offB[nt] = L * 128 + ((gg ^ (L & 7)) * 16);
  }

  auto stage = [&](int kt, int p) {       // (NA+2) async16/thread
    char* base = (char*)smem + p * BUFB;
    const unsigned ko = (unsigned)kt * 32;
#pragma unroll
    for (int i = 0; i < NA; i++)
      async16(Ab + oA[i] + ko, base + (i * 4 + wid) * 1024);
#pragma unroll
    for (int i = 0; i < 2; i++)
      async16(Bb + oB[i] + ko, base + ABYTES + (i * 4 + wid) * 1024);
  };

  f32x4 acc[MFR][4] = {};

  stage(0, 0);
#pragma unroll 2
  for (int t = 0; t < NT; t++) {
    __syncthreads();                      // tile-t loads drained (1 phase old)
    if (t + 1 < NT) stage(t + 1, (t + 1) & 1);
    const char* sA = (const char*)smem + (t & 1) * BUFB;
    const char* sB = sA + ABYTES;
    bf16x8 af[MFR], bfr[4];
#pragma unroll
    for (int mt = 0; mt < MFR; mt++) af[mt] = *(const bf16x8*)(sA + offA[mt]);
#pragma unroll
    for (int nt = 0; nt < 4; nt++) bfr[nt] = *(const bf16x8*)(sB + offB[nt]);
#pragma unroll
    for (int mt = 0; mt < MFR; mt++)
#pragma unroll
      for (int nt = 0; nt < 4; nt++)
        acc[mt][nt] = __builtin_amdgcn_mfma_f32_16x16x32_bf16(
            af[mt], bfr[nt], acc[mt][nt], 0, 0, 0);
  }

#pragma unroll
  for (int mt = 0; mt < MFR; mt++) {
    int gm = tileM + wm * (MFR * 16) + mt * 16 + quad * 4;
#pragma unroll
    for (int nt = 0; nt < 4; nt++) {
      int gn = tileN + wn * 64 + nt * 16 + col16;
      epi(bz, gm, gn, acc[mt][nt]);
    }
  }
}

extern "C" void kernel_launch(void* const* d_in, const int* in_sizes, int n_in,
                              void* d_out, int out_size, void* d_ws, size_t ws_size,
                              hipStream_t stream) {
  const float* x = (const float*)d_in[0];
  const float* ln_w = (const float*)d_in[1];
  const float* ln_b = (const float*)d_in[2];
  const float* uv_w = (const float*)d_in[3];
  const float* uv_b = (const float*)d_in[4];
  const float* gamma = (const float*)d_in[5];
  const float* beta = (const float*)d_in[6];
  const float* o_w = (const float*)d_in[7];
  const float* o_b = (const float*)d_in[8];
  const float* w_rel = (const float*)d_in[9];
  float* out = (float*)d_out;

  const int NOUT = 8388608;
  const size_t WS_NEEDED = 71303168;   // 68 MiB (>=69.4 MiB proven in R5)
  if (ws_size < WS_NEEDED) {
    float wsMiB = (float)(ws_size >> 20);
    fill_const<<<dim3(32768), dim3(256), 0, stream>>>(out, 1000.f + wsMiB, NOUT);
    return;
  }

  // ws: u [0,32M) (out2 alias), vT [32M,64M), o_wb [64M,68M)
  char* ws = (char*)d_ws;
  bf16_t* u = (bf16_t*)(ws + 0);
  bf16_t* out2 = u;
  bf16_t* vT = (bf16_t*)(ws + 33554432);
  bf16_t* o_wb = (bf16_t*)(ws + 67108864);
  // d_out dead-interval scratch (33.55 MB fp32 region):
  char* ob = (char*)d_out;
  bf16_t* xn = (bf16_t*)ob;                       // [0, 16,777,216)
  bf16_t* uv_wb = (bf16_t*)(ob + 16777216);       // [16,777,216, 25,427,968)
  bf16_t* baseb = (bf16_t*)(ob + 25427968);       // [25,427,968, 27,525,120)
  float* cosT = (float*)(ob + 27525120);          // [27,525,120, 27,656,192)
  float* sinT = (float*)(ob + 27656192);          // [27,656,192, 27,787,264)
  bf16_t* qb = (bf16_t*)ob;                       // [0, 2M)   K3->K4
  bf16_t* kb = (bf16_t*)(ob + 2097152);           // [2M, 4M)  K3->K4
  bf16_t* km = (bf16_t*)(ob + 4194304);           // [4M, 12M) K4->K5

  rope_table<<<dim3(128), dim3(256), 0, stream>>>(cosT, sinT);
  cvt_f32_bf16<<<dim3(4224), dim3(256), 0, stream>>>(uv_w, uv_wb, 1081344);
  cvt_f32_bf16<<<dim3(2048), dim3(256), 0, stream>>>(o_w, o_wb, 524288);
  ln_kernel<<<dim3(8192), dim3(256), 0, stream>>>(x, ln_w, ln_b, xn);
  // K2: silu(xn @ uv_wb^T + uv_b) -> u | vT | base: M=8192, N=4224, K=1024
  gemm_nt<4><<<dim3(64, 33, 1), dim3(256), 0, stream>>>(
      xn, uv_wb, 1024, 1024, 1024, 0L, 0L, EpiUV{uv_b, u, vT, baseb});
  rope_qk<<<dim3(8192), dim3(128), 0, stream>>>(baseb, gamma, beta, cosT, sinT, qb, kb);
  // K4: km = relu(q@k^T/512 + bias)^2: per batch M=N=512, K=128
  gemm_nt<4><<<dim3(4, 4, 16), dim3(256), 0, stream>>>(
      qb, kb, 128, 128, 128, (long)512 * 128, (long)512 * 128, EpiQK{w_rel, km});
  // K5: out2 = u * (km @ v): per batch M=512, N=2048, K=512
  gemm_nt<8><<<dim3(2, 16, 16), dim3(256), 0, stream>>>(
      km, vT, 512, 512, 512, (long)512 * 512, (long)2048 * 512, EpiAttn{u, out2});
  // K6: out = out2 @ o_wb^T + o_b + x: M=8192, N=1024, K=2048
  gemm_nt<4><<<dim3(64, 8, 1), dim3(256), 0, stream>>>(
      out2, o_wb, 2048, 2048, 2048, 0L, 0L, EpiOut{o_b, x, out});
}